// Round 4
// baseline (257.312 us; speedup 1.0000x reference)
//
#include <hip/hip_runtime.h>

#define HID      1024
#define INTER    2048
#define STATE    128
#define NH       32
#define PDIM     64
#define KCONV    4
#define QCH      256
#define CONV_DIM (INTER + 2*STATE)      // 2304
#define DPROJ    (2*INTER + 2*STATE + NH) // 4384
#define DPROJ_PAD 4480
#define BATCH    2
#define SEQ      2048
#define NCHUNK   (SEQ / QCH)            // 8
#define BL       (BATCH * SEQ)          // 4096

typedef unsigned short u16;
typedef unsigned int   u32;
typedef u16 u16x8 __attribute__((ext_vector_type(8)));
typedef u16 u16x4 __attribute__((ext_vector_type(4)));
typedef float f32x4 __attribute__((ext_vector_type(4)));
typedef __bf16 bf16x8 __attribute__((ext_vector_type(8)));

static __device__ __forceinline__ u16 f2bf(float f) {
    u32 u = __float_as_uint(f);
    return (u16)((u + 0x7FFFu + ((u >> 16) & 1u)) >> 16);
}
static __device__ __forceinline__ float bf2f(u16 v) {
    return __uint_as_float(((u32)v) << 16);
}
static __device__ __forceinline__ void gload_lds16(const void* g, void* l) {
    __builtin_amdgcn_global_load_lds(
        (const __attribute__((address_space(1))) void*)g,
        (__attribute__((address_space(3))) void*)l, 16, 0, 0);
}
// swizzled LDS u16-index helpers (row-major tiles; byte XOR at 16B granularity)
static __device__ __forceinline__ int swz64(int row, int slot) {   // 64B rows
    return ((row * 64 + slot * 16) ^ (((row >> 1) & 3) << 4)) >> 1;
}
static __device__ __forceinline__ int swz128(int row, int slot) {  // 128B rows
    return ((row * 128 + slot * 16) ^ ((row & 7) << 4)) >> 1;
}

// ---------------------------------------------------------------------------
// f32 -> bf16 conversion, 8 elems/thread; zero-fills [n, ntot).
// ---------------------------------------------------------------------------
__global__ __launch_bounds__(256)
void cvt_bf16(const float* __restrict__ src, u16* __restrict__ dst,
              long n, long ntot) {
    long i = ((long)blockIdx.x * 256 + threadIdx.x) * 8;
    if (i >= ntot) return;
    u16x8 o;
    if (i < n) {
        float4 a = *(const float4*)&src[i];
        float4 b = *(const float4*)&src[i + 4];
        o[0] = f2bf(a.x); o[1] = f2bf(a.y); o[2] = f2bf(a.z); o[3] = f2bf(a.w);
        o[4] = f2bf(b.x); o[5] = f2bf(b.y); o[6] = f2bf(b.z); o[7] = f2bf(b.w);
    } else {
        o = (u16x8)0;
    }
    *(u16x8*)&dst[i] = o;
}

// ---------------------------------------------------------------------------
// bf16 MFMA GEMM, 2-phase double-buffered pipeline (T3-min) + XCD swizzle:
//   C[M,Nstride](f32) = A[M,K] * W[Npad,K]^T    (128x128 tile, BK=32)
// Counted s_waitcnt vmcnt(4): next tile's loads stay in flight across the
// barrier; raw s_barrier avoids __syncthreads' vmcnt(0) drain.
// Requires K % 64 == 0, M % 128 == 0, gridDim.x*gridDim.y % 8 == 0.
// ---------------------------------------------------------------------------
__global__ __launch_bounds__(256)
void gemm_nt_bf16(const u16* __restrict__ A, const u16* __restrict__ W,
                  float* __restrict__ C, int Nstride, int Nreal, int K) {
    __shared__ __attribute__((aligned(16))) u16 As[2][128 * 32];
    __shared__ __attribute__((aligned(16))) u16 Ws[2][128 * 32];
    // bijective XCD-aware remap (nwg % 8 == 0)
    const int gx = gridDim.x;
    const int nwg = gx * gridDim.y;
    const int wg = blockIdx.y * gx + blockIdx.x;
    const int nid = (wg & 7) * (nwg >> 3) + (wg >> 3);
    const int bm = (nid / gx) * 128;
    const int bn = (nid % gx) * 128;

    const int t = threadIdx.x;
    const int lane = t & 63;
    const int wave = t >> 6;
    const int wr = wave >> 1, wc = wave & 1;
    const int fr = lane & 15;
    const int fq = lane >> 4;
    f32x4 acc[4][4];
#pragma unroll
    for (int m = 0; m < 4; ++m)
#pragma unroll
        for (int n = 0; n < 4; ++n) acc[m][n] = 0;

    const int crow = t >> 2;          // staging row 0..63 (chunk 1); +64 (chunk 2)
    const int sg = (t & 3) * 8;       // k-offset of the 16B chunk
    const u16* Ag = A + (size_t)(bm + crow) * K + sg;
    const u16* Wg = W + (size_t)(bn + crow) * K + sg;

#define STAGE(buf, k0)                                                        \
    do {                                                                      \
        gload_lds16(Ag + (k0),                  &As[buf][t * 8]);             \
        gload_lds16(Ag + (size_t)64 * K + (k0), &As[buf][2048 + t * 8]);      \
        gload_lds16(Wg + (k0),                  &Ws[buf][t * 8]);             \
        gload_lds16(Wg + (size_t)64 * K + (k0), &Ws[buf][2048 + t * 8]);      \
    } while (0)

#define COMPUTE(buf)                                                          \
    do {                                                                      \
        bf16x8 af[4], bw[4];                                                  \
        _Pragma("unroll")                                                     \
        for (int m = 0; m < 4; ++m)                                           \
            af[m] = *(const bf16x8*)&As[buf][(wr*64 + m*16 + fr)*32 + fq*8];  \
        _Pragma("unroll")                                                     \
        for (int n = 0; n < 4; ++n)                                           \
            bw[n] = *(const bf16x8*)&Ws[buf][(wc*64 + n*16 + fr)*32 + fq*8];  \
        _Pragma("unroll")                                                     \
        for (int m = 0; m < 4; ++m)                                           \
            _Pragma("unroll")                                                 \
            for (int n = 0; n < 4; ++n)                                       \
                acc[m][n] = __builtin_amdgcn_mfma_f32_16x16x32_bf16(          \
                    af[m], bw[n], acc[m][n], 0, 0, 0);                        \
    } while (0)

#define WAIT4() asm volatile("s_waitcnt vmcnt(4)" ::: "memory")
#define WAIT0() asm volatile("s_waitcnt vmcnt(0)" ::: "memory")
#define BAR()   asm volatile("s_barrier" ::: "memory")

    const int NT = K >> 5;            // even for K=1024/2048
    STAGE(0, 0);
    for (int tt = 0; tt < NT; tt += 2) {
        STAGE(1, (tt + 1) << 5);
        WAIT4();                      // tile tt (buf0) loads complete
        BAR();
        COMPUTE(0);
        BAR();
        if (tt + 2 < NT) {
            STAGE(0, (tt + 2) << 5);
            WAIT4();                  // tile tt+1 (buf1) loads complete
        } else {
            WAIT0();
        }
        BAR();
        COMPUTE(1);
        BAR();
    }
#undef STAGE
#undef COMPUTE
#undef WAIT4
#undef WAIT0
#undef BAR

#pragma unroll
    for (int m = 0; m < 4; ++m)
#pragma unroll
        for (int n = 0; n < 4; ++n) {
            int col = bn + wc * 64 + n * 16 + fr;
            if (col >= Nreal) continue;
            int row0 = bm + wr * 64 + m * 16 + fq * 4;
#pragma unroll
            for (int r = 0; r < 4; ++r)
                C[(size_t)(row0 + r) * Nstride + col] = acc[m][n][r];
        }
}

// ---------------------------------------------------------------------------
// Fused depthwise conv(K=4)+silu + transpose/pack:
//   x part  -> xT[b*2048 + c][L] bf16  (c in [0,2048))
//   B part  -> Bbf[b*L + l][128] bf16  AND  BT[b*128 + n][L] bf16
//   C part  -> Cbf[b*L + l][128] bf16
// ---------------------------------------------------------------------------
__global__ __launch_bounds__(256)
void convT_kernel(const float* __restrict__ zx,
                  const float* __restrict__ conv_w,
                  const float* __restrict__ conv_b,
                  u16* __restrict__ xT, u16* __restrict__ BT,
                  u16* __restrict__ Bbf, u16* __restrict__ Cbf) {
    __shared__ float s[64][65];
    const int c0 = blockIdx.x * 64;
    const int l0 = blockIdx.y * 64;
    const int b  = blockIdx.z;
    const int t  = threadIdx.x;
    const int j  = t & 63;
    const int g  = t >> 6;
    const int cg = c0 + j;
    const float w0 = conv_w[cg * 4 + 0], w1 = conv_w[cg * 4 + 1];
    const float w2 = conv_w[cg * 4 + 2], w3 = conv_w[cg * 4 + 3];
    const float bias = conv_b[cg];
    const float* col = zx + (size_t)b * SEQ * DPROJ + INTER + cg;
    int lbase = l0 + g * 16;
    float h3, h2, h1;
    h3 = (lbase - 3 >= 0) ? col[(size_t)(lbase - 3) * DPROJ] : 0.f;
    h2 = (lbase - 2 >= 0) ? col[(size_t)(lbase - 2) * DPROJ] : 0.f;
    h1 = (lbase - 1 >= 0) ? col[(size_t)(lbase - 1) * DPROJ] : 0.f;
#pragma unroll
    for (int k = 0; k < 16; ++k) {
        int l = lbase + k;
        float x0 = col[(size_t)l * DPROJ];
        float v = bias + h3 * w0 + h2 * w1 + h1 * w2 + x0 * w3;
        v = v / (1.f + __expf(-v));
        h3 = h2; h2 = h1; h1 = x0;
        s[g * 16 + k][j] = v;
        if (cg >= INTER) {
            int n = cg - INTER;
            if (n < STATE)
                Bbf[(size_t)(b * SEQ + l) * STATE + n] = f2bf(v);
            else
                Cbf[(size_t)(b * SEQ + l) * STATE + (n - STATE)] = f2bf(v);
        }
    }
    if (c0 >= INTER + STATE) return;
    __syncthreads();
    const int rr = t >> 2;
    const int lch = (t & 3) * 16;
    int cgout = c0 + rr;
    u16* orow;
    if (cgout < INTER) orow = xT + (size_t)(b * SEQ + cgout) * SEQ;
    else               orow = BT + (size_t)(b * STATE + (cgout - INTER)) * SEQ;
    u16x8 o0, o1;
#pragma unroll
    for (int e = 0; e < 8; ++e) o0[e] = f2bf(s[lch + e][rr]);
#pragma unroll
    for (int e = 0; e < 8; ++e) o1[e] = f2bf(s[lch + 8 + e][rr]);
    *(u16x8*)&orow[l0 + lch]     = o0;
    *(u16x8*)&orow[l0 + lch + 8] = o1;
}

// ---------------------------------------------------------------------------
// dt = softplus(dt_raw + dt_bias); seg = inclusive cumsum(dt * A) per chunk.
// ---------------------------------------------------------------------------
__global__ __launch_bounds__(256)
void dtseg_kernel(const float* __restrict__ zx,
                  const float* __restrict__ dt_bias,
                  const float* __restrict__ A_log,
                  float* __restrict__ dt_out,
                  float* __restrict__ seg_out) {
    int bid = blockIdx.x;
    int h = bid & 31, c = (bid >> 5) & 7, b = bid >> 8;
    int i = threadIdx.x;
    int bl = b * SEQ + c * QCH + i;
    float x = zx[(size_t)bl * DPROJ + INTER + CONV_DIM + h] + dt_bias[h];
    float dtv = (x > 20.f) ? x : log1pf(expf(x));
    dt_out[bl * NH + h] = dtv;
    float Ah = -expf(A_log[h]);
    __shared__ float s[QCH];
    s[i] = dtv * Ah;
    __syncthreads();
    for (int off = 1; off < QCH; off <<= 1) {
        float add = (i >= off) ? s[i - off] : 0.f;
        __syncthreads();
        s[i] += add;
        __syncthreads();
    }
    seg_out[bl * NH + h] = s[i];
}

// ---------------------------------------------------------------------------
// CB[bc,i,j] = sum_n C[i,n]*B[j,n] via MFMA. grid (jt=4, it=4, bc=16).
// ---------------------------------------------------------------------------
__global__ __launch_bounds__(256)
void cb_kernel(const u16* __restrict__ Cbf, const u16* __restrict__ Bbf,
               float* __restrict__ CB) {
    const int jt = blockIdx.x, it = blockIdx.y;
    if (jt > it) return;
    const int bc = blockIdx.z;
    const int b = bc >> 3, c = bc & 7;
    __shared__ __attribute__((aligned(16))) u16 Ct[64 * 32];
    __shared__ __attribute__((aligned(16))) u16 Bt[64 * 32];
    const int t = threadIdx.x;
    const int lane = t & 63, wave = t >> 6;
    const int wr = wave >> 1, wc = wave & 1;
    const int fr = lane & 15, fq = lane >> 4;
    const int l0 = b * SEQ + c * QCH;
    f32x4 acc[2][2];
#pragma unroll
    for (int m = 0; m < 2; ++m)
#pragma unroll
        for (int n = 0; n < 2; ++n) acc[m][n] = 0;
    const int srow = t >> 2, sslot = t & 3;
    for (int n0 = 0; n0 < STATE; n0 += 32) {
        gload_lds16(Cbf + (size_t)(l0 + it * 64 + srow) * STATE + n0 +
                        8 * (sslot ^ ((srow >> 1) & 3)), &Ct[t * 8]);
        gload_lds16(Bbf + (size_t)(l0 + jt * 64 + srow) * STATE + n0 +
                        8 * (sslot ^ ((srow >> 1) & 3)), &Bt[t * 8]);
        __syncthreads();
        bf16x8 af[2], bw[2];
#pragma unroll
        for (int m = 0; m < 2; ++m)
            af[m] = *(const bf16x8*)&Ct[swz64(wr * 32 + m * 16 + fr, fq)];
#pragma unroll
        for (int n = 0; n < 2; ++n)
            bw[n] = *(const bf16x8*)&Bt[swz64(wc * 32 + n * 16 + fr, fq)];
#pragma unroll
        for (int m = 0; m < 2; ++m)
#pragma unroll
            for (int n = 0; n < 2; ++n)
                acc[m][n] = __builtin_amdgcn_mfma_f32_16x16x32_bf16(
                    af[m], bw[n], acc[m][n], 0, 0, 0);
        __syncthreads();
    }
#pragma unroll
    for (int m = 0; m < 2; ++m)
#pragma unroll
        for (int n = 0; n < 2; ++n) {
            int i = it * 64 + wr * 32 + m * 16 + fq * 4;
            int jj = jt * 64 + wc * 32 + n * 16 + fr;
#pragma unroll
            for (int r = 0; r < 4; ++r)
                CB[((size_t)bc * QCH + i + r) * QCH + jj] = acc[m][n][r];
        }
}

// ---------------------------------------------------------------------------
// states[b,c,h,p,n] = sum_j x[j,p]*dt[j]*exp(seg_last-seg[j]) * B[j,n]
// ---------------------------------------------------------------------------
__global__ __launch_bounds__(256)
void states_kernel(const u16* __restrict__ xT, const u16* __restrict__ BT,
                   const float* __restrict__ dt, const float* __restrict__ seg,
                   float* __restrict__ states) {
    int bid = blockIdx.x;
    int h = bid & 31, c = (bid >> 5) & 7, b = bid >> 8;
    __shared__ float dd[QCH];
    __shared__ __attribute__((aligned(16))) u16 At[64 * 32];
    __shared__ __attribute__((aligned(16))) u16 Bt[128 * 32];
    const int t = threadIdx.x;
    const int lane = t & 63, wave = t >> 6;
    const int wr = wave >> 1, wc = wave & 1;
    const int fr = lane & 15, fq = lane >> 4;
    const int l0 = b * SEQ + c * QCH;
    {
        float seg_last = seg[(size_t)(l0 + QCH - 1) * NH + h];
        dd[t] = dt[(size_t)(l0 + t) * NH + h] *
                __expf(seg_last - seg[(size_t)(l0 + t) * NH + h]);
    }
    __syncthreads();
    f32x4 acc[2][4];
#pragma unroll
    for (int m = 0; m < 2; ++m)
#pragma unroll
        for (int n = 0; n < 4; ++n) acc[m][n] = 0;
    const int ap = t >> 2, ajs = t & 3;
    const u16* xrow = xT + (size_t)(b * SEQ + h * PDIM + ap) * SEQ + c * QCH;
    for (int j0 = 0; j0 < QCH; j0 += 32) {
        u16x8 v = *(const u16x8*)&xrow[j0 + ajs * 8];
        u16x8 o;
#pragma unroll
        for (int e = 0; e < 8; ++e)
            o[e] = f2bf(bf2f(v[e]) * dd[j0 + ajs * 8 + e]);
        *(u16x8*)&At[swz64(ap, ajs)] = o;
#pragma unroll
        for (int q = 0; q < 2; ++q) {
            int chunk = t + 256 * q;
            int row = chunk >> 2, slot = chunk & 3;
            gload_lds16(BT + (size_t)(b * STATE + row) * SEQ + c * QCH + j0 +
                            8 * (slot ^ ((row >> 1) & 3)), &Bt[chunk * 8]);
        }
        __syncthreads();
        bf16x8 af[2], bw[4];
#pragma unroll
        for (int m = 0; m < 2; ++m)
            af[m] = *(const bf16x8*)&At[swz64(wr * 32 + m * 16 + fr, fq)];
#pragma unroll
        for (int n = 0; n < 4; ++n)
            bw[n] = *(const bf16x8*)&Bt[swz64(wc * 64 + n * 16 + fr, fq)];
#pragma unroll
        for (int m = 0; m < 2; ++m)
#pragma unroll
            for (int n = 0; n < 4; ++n)
                acc[m][n] = __builtin_amdgcn_mfma_f32_16x16x32_bf16(
                    af[m], bw[n], acc[m][n], 0, 0, 0);
        __syncthreads();
    }
    size_t base = ((((size_t)b * NCHUNK + c) * NH + h) * PDIM) * STATE;
#pragma unroll
    for (int m = 0; m < 2; ++m)
#pragma unroll
        for (int n = 0; n < 4; ++n) {
            int p = wr * 32 + m * 16 + fq * 4;
            int nn = wc * 64 + n * 16 + fr;
#pragma unroll
            for (int r = 0; r < 4; ++r)
                states[base + (size_t)(p + r) * STATE + nn] = acc[m][n][r];
        }
}

// ---------------------------------------------------------------------------
// Inter-chunk scan (in place) + bf16 copy of the carried (prev) states.
// ---------------------------------------------------------------------------
__global__ void scan_kernel(float* __restrict__ states,
                            const float* __restrict__ seg,
                            u16* __restrict__ prevbf) {
    int tid = blockIdx.x * blockDim.x + threadIdx.x;
    int n = tid & 127, p = (tid >> 7) & 63, h = (tid >> 13) & 31, b = tid >> 18;
    float carry = 0.f;
    for (int c = 0; c < NCHUNK; ++c) {
        size_t idx = ((((size_t)b * NCHUNK + c) * NH + h) * PDIM + p) * STATE + n;
        float st = states[idx];
        states[idx] = carry;
        prevbf[idx] = f2bf(carry);
        float dec = __expf(seg[(size_t)(b*SEQ + c*QCH + QCH - 1) * NH + h]);
        carry = carry * dec + st;
    }
}

// ---------------------------------------------------------------------------
// Fused Yo + Yd + D*x.
// ---------------------------------------------------------------------------
__global__ __launch_bounds__(256)
void ydo_kernel(const u16* __restrict__ xT, const u16* __restrict__ Cbf,
                const u16* __restrict__ prevbf, const float* __restrict__ CB,
                const float* __restrict__ dt, const float* __restrict__ seg,
                const float* __restrict__ Dv, float* __restrict__ y) {
    int bid = blockIdx.x;
    int h = bid & 31, c = (bid >> 5) & 7, b = bid >> 8;
    __shared__ float seg_s[QCH], sge_s[QCH], dtv_s[QCH];
    __shared__ __attribute__((aligned(16))) u16 big[QCH * 64];
    __shared__ __attribute__((aligned(16))) u16 small[64 * 64];
    const int t = threadIdx.x;
    const int lane = t & 63, w = t >> 6;
    const int fr = lane & 15, fq = lane >> 4;
    const int l0 = b * SEQ + c * QCH;
    {
        float sv = seg[(size_t)(l0 + t) * NH + h];
        seg_s[t] = sv;
        sge_s[t] = __expf(sv);
        dtv_s[t] = dt[(size_t)(l0 + t) * NH + h];
    }
    __syncthreads();
    f32x4 acc[4][4];
#pragma unroll
    for (int m = 0; m < 4; ++m)
#pragma unroll
        for (int n = 0; n < 4; ++n) acc[m][n] = 0;

    const size_t pvbase = ((((size_t)b * NCHUNK + c) * NH + h) * PDIM) * STATE;
    for (int ks = 0; ks < 4; ++ks) {
#pragma unroll
        for (int q = 0; q < 4; ++q) {
            int chunk = t + 256 * q;
            int row = chunk >> 2, slot = chunk & 3;
            gload_lds16(Cbf + (size_t)(l0 + row) * STATE + ks * 32 +
                            8 * (slot ^ ((row >> 1) & 3)), &big[chunk * 8]);
        }
        {
            int row = t >> 2, slot = t & 3;
            gload_lds16(prevbf + pvbase + (size_t)row * STATE + ks * 32 +
                            8 * (slot ^ ((row >> 1) & 3)), &small[t * 8]);
        }
        __syncthreads();
        bf16x8 af[4], bw[4];
#pragma unroll
        for (int m = 0; m < 4; ++m)
            af[m] = *(const bf16x8*)&big[swz64(64 * m + 16 * w + fr, fq)];
#pragma unroll
        for (int n = 0; n < 4; ++n)
            bw[n] = *(const bf16x8*)&small[swz64(16 * n + fr, fq)];
#pragma unroll
        for (int m = 0; m < 4; ++m)
#pragma unroll
            for (int n = 0; n < 4; ++n)
                acc[m][n] = __builtin_amdgcn_mfma_f32_16x16x32_bf16(
                    af[m], bw[n], acc[m][n], 0, 0, 0);
        __syncthreads();
    }
#pragma unroll
    for (int m = 0; m < 4; ++m)
#pragma unroll
        for (int n = 0; n < 4; ++n)
#pragma unroll
            for (int r = 0; r < 4; ++r)
                acc[m][n][r] *= sge_s[64 * m + 16 * w + fq * 4 + r];

    const float* CBrow = CB + (size_t)(b * NCHUNK + c) * QCH * QCH;
    for (int jt = 0; jt < 4; ++jt) {
        const int j0 = jt * 64;
        const int mcol = t & 63;
        for (int r = j0 + (t >> 6); r < QCH; r += 4) {
            float v = 0.f;
            if (mcol <= r - j0)
                v = CBrow[(size_t)r * QCH + j0 + mcol] *
                    __expf(seg_s[r] - seg_s[j0 + mcol]) * dtv_s[j0 + mcol];
            big[((r * 128 + mcol * 2) ^ ((r & 7) << 4)) >> 1] = f2bf(v);
        }
#pragma unroll
        for (int q = 0; q < 2; ++q) {
            int chunk = t + 256 * q;
            int row = chunk >> 3, slot = chunk & 7;
            gload_lds16(xT + (size_t)(b * SEQ + h * PDIM + row) * SEQ +
                            c * QCH + j0 + 8 * (slot ^ (row & 7)),
                        &small[chunk * 8]);
        }
        __syncthreads();
#pragma unroll
        for (int ks = 0; ks < 2; ++ks) {
#pragma unroll
            for (int m = 0; m < 4; ++m) {
                if (64 * m + 16 * w >= j0) {
                    bf16x8 af = *(const bf16x8*)
                        &big[swz128(64 * m + 16 * w + fr, ks * 4 + fq)];
#pragma unroll
                    for (int n = 0; n < 4; ++n) {
                        bf16x8 bw = *(const bf16x8*)
                            &small[swz128(16 * n + fr, ks * 4 + fq)];
                        acc[m][n] = __builtin_amdgcn_mfma_f32_16x16x32_bf16(
                            af, bw, acc[m][n], 0, 0, 0);
                    }
                }
            }
        }
        __syncthreads();
    }
    const float Dh = Dv[h];
#pragma unroll
    for (int m = 0; m < 4; ++m) {
        int i = 64 * m + 16 * w + fq * 4;
#pragma unroll
        for (int n = 0; n < 4; ++n) {
            int p = 16 * n + fr;
            u16x4 xv = *(const u16x4*)&xT[(size_t)(b * SEQ + h * PDIM + p) * SEQ +
                                          c * QCH + i];
#pragma unroll
            for (int r = 0; r < 4; ++r)
                y[(size_t)(l0 + i + r) * INTER + h * PDIM + p] =
                    acc[m][n][r] + Dh * bf2f(xv[r]);
        }
    }
}

// ---------------------------------------------------------------------------
// yg = y * silu(z); RMS-norm; * norm_weight; emit bf16 for out_proj GEMM.
// ---------------------------------------------------------------------------
__global__ __launch_bounds__(256)
void gatenorm_kernel(const float* __restrict__ y, const float* __restrict__ zx,
                     const float* __restrict__ nw, u16* __restrict__ ybf) {
    int bl = blockIdx.x;
    int t = threadIdx.x;
    const float* yrow = y  + (size_t)bl * INTER + t * 8;
    const float* zrow = zx + (size_t)bl * DPROJ + t * 8;
    float4 y0 = *(const float4*)yrow,       y1 = *(const float4*)(yrow + 4);
    float4 z0 = *(const float4*)zrow,       z1 = *(const float4*)(zrow + 4);
    float yv[8] = {y0.x,y0.y,y0.z,y0.w,y1.x,y1.y,y1.z,y1.w};
    float zv[8] = {z0.x,z0.y,z0.z,z0.w,z1.x,z1.y,z1.z,z1.w};
    float g[8];
    float ss = 0.f;
#pragma unroll
    for (int i = 0; i < 8; ++i) {
        g[i] = yv[i] * (zv[i] / (1.f + expf(-zv[i])));
        ss += g[i] * g[i];
    }
    for (int off = 32; off > 0; off >>= 1) ss += __shfl_xor(ss, off, 64);
    __shared__ float red[4];
    if ((t & 63) == 0) red[t >> 6] = ss;
    __syncthreads();
    float tot = red[0] + red[1] + red[2] + red[3];
    float scale = rsqrtf(tot / INTER + 1e-6f);
    const float* nwp = nw + t * 8;
    u16x8 o;
#pragma unroll
    for (int i = 0; i < 8; ++i) o[i] = f2bf(g[i] * scale * nwp[i]);
    *(u16x8*)&ybf[(size_t)bl * INTER + t * 8] = o;
}

// ---------------------------------------------------------------------------
extern "C" void kernel_launch(void* const* d_in, const int* in_sizes, int n_in,
                              void* d_out, int out_size, void* d_ws, size_t ws_size,
                              hipStream_t stream) {
    const float* hidden     = (const float*)d_in[0];
    const float* in_proj_w  = (const float*)d_in[1];
    const float* conv_w     = (const float*)d_in[2];
    const float* conv_b     = (const float*)d_in[3];
    const float* dt_bias    = (const float*)d_in[4];
    const float* A_log      = (const float*)d_in[5];
    const float* Dv         = (const float*)d_in[6];
    const float* norm_w     = (const float*)d_in[7];
    const float* out_proj_w = (const float*)d_in[8];
    float* out = (float*)d_out;

    float* ws     = (float*)d_ws;
    float* zx     = ws;                                      // 17,956,864
    float* dtb    = zx   + (size_t)BL * DPROJ;               //    131,072
    float* segb   = dtb  + (size_t)BL * NH;                  //    131,072
    float* CB     = segb + (size_t)BL * NH;                  //  1,048,576
    float* states = CB   + (size_t)BATCH*NCHUNK*QCH*QCH;     // 16,777,216
    float* y      = states + (size_t)BATCH*NCHUNK*NH*PDIM*STATE; // 8,388,608
    float* tail   = y + (size_t)BL * INTER;
    u16* xT     = (u16*)tail;                                // 8,388,608 u16
    u16* BT     = xT   + (size_t)BL * INTER;                 //   524,288
    u16* Bbf    = BT   + (size_t)BATCH * STATE * SEQ;        //   524,288
    u16* Cbf    = Bbf  + (size_t)BL * STATE;                 //   524,288
    u16* prevbf = Cbf  + (size_t)BL * STATE;                 // 16,777,216
    u16* W2bf   = prevbf + (size_t)BATCH*NCHUNK*NH*PDIM*STATE; // 2,097,152
    u16* Abf = (u16*)states;
    u16* Wbf = (u16*)states + (size_t)BL * HID;
    u16* ybf = xT;

    cvt_bf16<<<(BL*HID)/2048, 256, 0, stream>>>(hidden, Abf, (long)BL*HID, (long)BL*HID);
    cvt_bf16<<<((long)DPROJ_PAD*HID)/2048, 256, 0, stream>>>(in_proj_w, Wbf,
        (long)DPROJ*HID, (long)DPROJ_PAD*HID);
    cvt_bf16<<<((long)HID*INTER)/2048, 256, 0, stream>>>(out_proj_w, W2bf,
        (long)HID*INTER, (long)HID*INTER);

    gemm_nt_bf16<<<dim3(DPROJ_PAD/128, BL/128), 256, 0, stream>>>(
        Abf, Wbf, zx, DPROJ, DPROJ, HID);

    dtseg_kernel<<<BATCH * NCHUNK * NH, 256, 0, stream>>>(zx, dt_bias, A_log, dtb, segb);
    convT_kernel<<<dim3(CONV_DIM/64, SEQ/64, BATCH), 256, 0, stream>>>(
        zx, conv_w, conv_b, xT, BT, Bbf, Cbf);
    cb_kernel<<<dim3(4, 4, BATCH*NCHUNK), 256, 0, stream>>>(Cbf, Bbf, CB);
    states_kernel<<<BATCH * NCHUNK * NH, 256, 0, stream>>>(xT, BT, dtb, segb, states);
    scan_kernel<<<(BATCH * NH * PDIM * STATE) / 256, 256, 0, stream>>>(states, segb, prevbf);
    ydo_kernel<<<BATCH * NCHUNK * NH, 256, 0, stream>>>(
        xT, Cbf, prevbf, CB, dtb, segb, Dv, y);
    gatenorm_kernel<<<BL, 256, 0, stream>>>(y, zx, norm_w, ybf);
    gemm_nt_bf16<<<dim3(HID/128, BL/128), 256, 0, stream>>>(
        ybf, W2bf, out, HID, HID, INTER);
}